// Round 2
// baseline (75.295 us; speedup 1.0000x reference)
//
#include <hip/hip_runtime.h>
#include <hip/hip_bf16.h>
#include <math.h>

#define FDIM  128
#define BATCH 4096
#define CNUM  10000

typedef __attribute__((ext_vector_type(8))) short short8;   // 8 bf16 = 4 VGPRs (MFMA A/B frag)
typedef __attribute__((ext_vector_type(4))) float f32x4;    // MFMA C/D frag / float4 store

// ---------------- ws layout (bytes) ----------------
#define WS_FEATB 0            // 4096*128 bf16  = 1048576
#define WS_WB    1048576      // 10000*128 bf16 = 2560000
#define WS_F2    3608576      // 4096 f32
#define WS_W2    3624960      // 10000 f32
#define WS_COR   3664960      // 4096 f32

// exp(-m/1.8) = 2^(-m * C2);  C2 = 1/(1.8*ln2)
#define C2 0.80178372573096f

// Kernel 1: fused prep (f32->bf16 convert + row norms) and cor gather.
// waves [0, BATCH+CNUM)          : convert + squared norm (2 f32/lane)
// waves [BATCH+CNUM, +BATCH)     : cor[s] = exp(-||feat[s]-weights[label[s]]||^2/1.8)
__global__ void prep_cor_kernel(const float* __restrict__ feat,
                                const float* __restrict__ weights,
                                const int* __restrict__ label,
                                __hip_bfloat16* __restrict__ featb,
                                __hip_bfloat16* __restrict__ wb,
                                float* __restrict__ f2,
                                float* __restrict__ w2,
                                float* __restrict__ cor) {
    int gw   = (blockIdx.x * blockDim.x + threadIdx.x) >> 6;
    int lane = threadIdx.x & 63;
    if (gw < BATCH + CNUM) {
        const float* src;
        __hip_bfloat16* dst;
        float* nrm;
        if (gw < BATCH) { src = feat    + (size_t)gw * FDIM; dst = featb + (size_t)gw * FDIM; nrm = f2 + gw; }
        else            { int r = gw - BATCH;
                          src = weights + (size_t)r  * FDIM; dst = wb    + (size_t)r  * FDIM; nrm = w2 + r; }
        float2 v = ((const float2*)src)[lane];
        __hip_bfloat162 b2;
        b2.x = __float2bfloat16(v.x);
        b2.y = __float2bfloat16(v.y);
        ((__hip_bfloat162*)dst)[lane] = b2;
        float ss = v.x * v.x + v.y * v.y;
        #pragma unroll
        for (int off = 32; off; off >>= 1) ss += __shfl_down(ss, off, 64);
        if (lane == 0) *nrm = ss;
    } else {
        int s = gw - (BATCH + CNUM);
        if (s >= BATCH) return;
        int lab = label[s];
        float2 f = ((const float2*)(feat    + (size_t)s   * FDIM))[lane];
        float2 w = ((const float2*)(weights + (size_t)lab * FDIM))[lane];
        float dx = f.x - w.x, dy = f.y - w.y;
        float ss = dx * dx + dy * dy;
        #pragma unroll
        for (int off = 32; off; off >>= 1) ss += __shfl_down(ss, off, 64);
        if (lane == 0) cor[s] = __expf(-ss * (1.0f / 1.8f));
    }
}

// Kernel 2: GEMM + fused scale-reduction + epilogue.
// Orientation: A = wb (classes = M), B = featb (batch = N).
// C/D layout (16x16x32): col = lane&15 -> batch sample, row = kh*4+reg -> class.
// => each lane's f32x4 is 4 CONSECUTIVE classes of one output row -> dwordx4 store.
// 128x128 block tile, 4 waves of 64(classes) x 64(batch).
// Scale: every block deterministically reduces cor[0..4095] (identical order
// and result in all blocks), ls2 = log2(log(C-1)/max(mean,0.5)).
__launch_bounds__(256, 2)
__global__ void gemm_kernel(const __hip_bfloat16* __restrict__ featb,
                            const __hip_bfloat16* __restrict__ wb,
                            const float* __restrict__ f2,
                            const float* __restrict__ w2,
                            const float* __restrict__ cor,
                            float* __restrict__ out) {
    __shared__ float red[4];
    __shared__ float s_ls2;
    int tid  = threadIdx.x;
    int wid  = tid >> 6;
    int lane = tid & 63;

    // ---- deterministic scale reduction (same in every block) ----
    {
        float s = 0.0f;
        #pragma unroll
        for (int i = 0; i < BATCH / 256; i++) s += cor[tid + i * 256];
        #pragma unroll
        for (int off = 32; off; off >>= 1) s += __shfl_down(s, off, 64);
        if ((tid & 63) == 0) red[tid >> 6] = s;
        __syncthreads();
        if (tid == 0) {
            float avg = (red[0] + red[1] + red[2] + red[3]) * (1.0f / BATCH);
            avg = fmaxf(avg, 0.5f);
            s_ls2 = log2f(logf((float)(CNUM - 1)) / avg);
        }
        __syncthreads();
    }
    float ls2 = s_ls2;

    const int MT = (CNUM + 127) / 128;     // 79 class tiles (last partial)
    int mt = blockIdx.x % MT;
    int nt = blockIdx.x / MT;              // 32 batch tiles
    int r16 = lane & 15;
    int kh  = lane >> 4;
    int mbase = mt * 128 + (wid >> 1) * 64;   // class base for this wave
    int nbase = nt * 128 + (wid & 1) * 64;    // batch base for this wave

    const short* A = (const short*)wb;     // classes
    const short* B = (const short*)featb;  // batch

    int arow[4], brow[4];
    #pragma unroll
    for (int m = 0; m < 4; m++) {
        int c = mbase + m * 16 + r16;
        arow[m] = c < CNUM ? c : CNUM - 1;    // clamp reads; stores masked below
    }
    #pragma unroll
    for (int n = 0; n < 4; n++) brow[n] = nbase + n * 16 + r16;

    f32x4 acc[4][4];
    #pragma unroll
    for (int m = 0; m < 4; m++)
        #pragma unroll
        for (int n = 0; n < 4; n++) acc[m][n] = (f32x4){0.f, 0.f, 0.f, 0.f};

    #pragma unroll
    for (int kk = 0; kk < 4; kk++) {
        int ko = kk * 32 + kh * 8;          // elements; 16B-aligned chunk of the 256B row
        short8 a[4], b[4];
        #pragma unroll
        for (int m = 0; m < 4; m++) a[m] = *(const short8*)(A + (size_t)arow[m] * FDIM + ko);
        #pragma unroll
        for (int n = 0; n < 4; n++) b[n] = *(const short8*)(B + (size_t)brow[n] * FDIM + ko);
        #pragma unroll
        for (int m = 0; m < 4; m++)
            #pragma unroll
            for (int n = 0; n < 4; n++)
                acc[m][n] = __builtin_amdgcn_mfma_f32_16x16x32_bf16(a[m], b[n], acc[m][n], 0, 0, 0);
    }

    // ---- epilogue: out[bn][cm0..cm0+3] = 2^(ls2 - metric*C2), dwordx4 stores ----
    float f2n[4];
    #pragma unroll
    for (int n = 0; n < 4; n++) f2n[n] = f2[nbase + n * 16 + r16];

    #pragma unroll
    for (int m = 0; m < 4; m++) {
        int cm0 = mbase + m * 16 + kh * 4;     // first of 4 consecutive classes
        bool ok = cm0 < CNUM;                   // CNUM%4==0 -> float4 never straddles
        f32x4 w4 = *(const f32x4*)(w2 + (ok ? cm0 : 0));
        #pragma unroll
        for (int n = 0; n < 4; n++) {
            f32x4 v;
            #pragma unroll
            for (int r = 0; r < 4; r++) {
                float t = fmaf(-2.0f, acc[m][n][r], f2n[n] + w4[r]);
                t = fmaxf(t, 0.0f);
                v[r] = exp2f(fmaf(t, -C2, ls2));
            }
            if (ok) {
                size_t bn = (size_t)(nbase + n * 16 + r16);
                *(f32x4*)(out + bn * CNUM + cm0) = v;
            }
        }
    }
}

extern "C" void kernel_launch(void* const* d_in, const int* in_sizes, int n_in,
                              void* d_out, int out_size, void* d_ws, size_t ws_size,
                              hipStream_t stream) {
    (void)in_sizes; (void)n_in; (void)out_size; (void)ws_size;
    const float* feat    = (const float*)d_in[0];
    const float* weights = (const float*)d_in[1];
    const int*   label   = (const int*)d_in[2];
    float* out = (float*)d_out;
    char*  ws  = (char*)d_ws;

    __hip_bfloat16* featb = (__hip_bfloat16*)(ws + WS_FEATB);
    __hip_bfloat16* wb    = (__hip_bfloat16*)(ws + WS_WB);
    float* f2  = (float*)(ws + WS_F2);
    float* w2  = (float*)(ws + WS_W2);
    float* cor = (float*)(ws + WS_COR);

    // waves: BATCH+CNUM converts + BATCH cor gathers, 4 waves/block
    const int total_waves = BATCH + CNUM + BATCH;
    prep_cor_kernel<<<(total_waves + 3) / 4, 256, 0, stream>>>(
        feat, weights, label, featb, wb, f2, w2, cor);

    const int MT = (CNUM + 127) / 128;   // 79
    gemm_kernel<<<MT * (BATCH / 128), 256, 0, stream>>>(featb, wb, f2, w2, cor, out);
}